// Round 1
// baseline (227.019 us; speedup 1.0000x reference)
//
#include <hip/hip_runtime.h>
#include <hip/hip_bf16.h>

#define B_ 16
#define H_ 128
#define L_ 4096
#define N_ 64
#define DT_ 0.01f

typedef __bf16 bf16;
typedef __bf16 bf16x8 __attribute__((ext_vector_type(8)));
typedef __bf16 bf16x4 __attribute__((ext_vector_type(4)));
typedef float f32x4 __attribute__((ext_vector_type(4)));

// ---------------------------------------------------------------- k_prep ----
// Cast MLP weights fp32 -> bf16 into workspace (done every launch; ws is
// re-poisoned before every timed call).
__global__ void k_prep(const float* __restrict__ w1, const float* __restrict__ w2,
                       bf16* __restrict__ w1b, bf16* __restrict__ w2b) {
    int i = blockIdx.x * blockDim.x + threadIdx.x;
    if (i < H_ * H_) {
        w1b[i] = (bf16)w1[i];
        w2b[i] = (bf16)w2[i];
    }
}

// ----------------------------------------------------------------- k_ssm ----
// One wave (64 lanes) per (b,h). Lane n owns complex mode n:
//   s_n[l] = A_n s_n[l-1] + u[l],  A_n = exp(DT*lambda_n)
//   y[l]   = sum_n Re(W_n s_n[l]) + d_h u[l]
// Per 64-step chunk: contributions scattered to padded LDS [step][lane],
// then transposed reduce: lane t sums over n -> y[l0+t]. Store y as bf16
// (only the MLP consumes it).
__global__ __launch_bounds__(64) void k_ssm(
        const float* __restrict__ u,
        const float* __restrict__ lre, const float* __restrict__ lim,
        const float* __restrict__ wre, const float* __restrict__ wim,
        const float* __restrict__ dv,
        bf16* __restrict__ ybf) {
    __shared__ float part[64 * 65];   // [step j][lane n], pad 65 -> conflict-free transpose
    __shared__ float ub[64];          // u chunk for broadcast reads

    const int lane = threadIdx.x;         // mode n
    const int bh   = blockIdx.x;          // b*H + h
    const int h    = bh & (H_ - 1);

    const int idx = h * N_ + lane;
    const float lr = lre[idx];
    const float li = lim[idx];
    const float e  = expf(DT_ * lr);
    const float ar = e * cosf(DT_ * li);
    const float ai = e * sinf(DT_ * li);
    const float wr = wre[idx];
    const float wi = wim[idx];
    const float dh = dv[h];

    const float* __restrict__ up = u   + (size_t)bh * L_;
    bf16*        __restrict__ yp = ybf + (size_t)bh * L_;

    float sr = 0.f, si = 0.f;

    for (int c = 0; c < L_ / 64; ++c) {
        const float uv = up[c * 64 + lane];
        ub[lane] = uv;
        __syncthreads();

        #pragma unroll
        for (int j = 0; j < 64; ++j) {
            const float uj = ub[j];                       // LDS broadcast
            const float nsr = fmaf(-ai, si, fmaf(ar, sr, uj));
            const float nsi = fmaf(ar, si, ai * sr);
            sr = nsr; si = nsi;
            part[j * 65 + lane] = fmaf(wr, sr, -(wi * si));
        }
        __syncthreads();

        float acc = dh * uv;
        #pragma unroll
        for (int nn = 0; nn < 64; ++nn) acc += part[lane * 65 + nn];
        yp[c * 64 + lane] = (bf16)acc;
        __syncthreads();
    }
}

// ----------------------------------------------------------------- k_mlp ----
// Fused 2-layer 1x1-conv MLP with ReLU, bf16 MFMA (16x16x32).
// Block = one (b, 64-wide l tile); 4 waves; wave w owns output rows
// [32w, 32w+32). Layouts (m89/m120-verified):
//   A[m][k]: m=lane&15, k=(lane>>4)*8+j ; B[k][n]: n=lane&15, k=(lane>>4)*8+j
//   C/D:     col=lane&15, row=(lane>>4)*4+reg
#define YSTR 136   // 128 + 8: keeps ds_read_b128 16B-aligned, balanced banks
__global__ __launch_bounds__(256) void k_mlp(
        const bf16* __restrict__ ybf,
        const bf16* __restrict__ w1b, const bf16* __restrict__ w2b,
        const float* __restrict__ b1, const float* __restrict__ b2,
        float* __restrict__ out) {
    __shared__ bf16 YT [64 * YSTR];   // y tile transposed: [l_local][h]
    __shared__ bf16 H1T[64 * YSTR];   // hidden transposed:  [l_local][o]
    __shared__ float B1s[H_], B2s[H_];

    const int tid = threadIdx.x;
    const int b   = blockIdx.x >> 6;
    const int lt  = blockIdx.x & 63;
    const int l0  = lt * 64;

    if (tid < H_) { B1s[tid] = b1[tid]; B2s[tid] = b2[tid]; }

    // ---- stage y tile (128h x 64l) transposed into LDS ----
    {
        const int h  = tid >> 1;
        const int lh = (tid & 1) * 32;
        const bf16x8* src = (const bf16x8*)(ybf + ((size_t)b * H_ + h) * L_ + l0 + lh);
        #pragma unroll
        for (int v = 0; v < 4; ++v) {
            bf16x8 d = src[v];
            #pragma unroll
            for (int e = 0; e < 8; ++e) YT[(lh + v * 8 + e) * YSTR + h] = d[e];
        }
    }
    __syncthreads();

    const int lane = tid & 63;
    const int wv   = tid >> 6;
    const int m    = lane & 15;   // A-row / B-col / C-col
    const int q    = lane >> 4;   // quad
    const int m0   = wv * 32;

    // ---- layer 1: h1 = relu(W1 @ y + b1) ----
    f32x4 acc[2][4];
    #pragma unroll
    for (int i = 0; i < 2; ++i)
        #pragma unroll
        for (int nt = 0; nt < 4; ++nt) acc[i][nt] = (f32x4){0.f, 0.f, 0.f, 0.f};

    #pragma unroll
    for (int kb = 0; kb < 4; ++kb) {
        const bf16x8 a0 = *(const bf16x8*)(w1b + (size_t)(m0 + m)      * H_ + kb * 32 + q * 8);
        const bf16x8 a1 = *(const bf16x8*)(w1b + (size_t)(m0 + 16 + m) * H_ + kb * 32 + q * 8);
        #pragma unroll
        for (int nt = 0; nt < 4; ++nt) {
            const bf16x8 bfr = *(const bf16x8*)(&YT[(nt * 16 + m) * YSTR + kb * 32 + q * 8]);
            acc[0][nt] = __builtin_amdgcn_mfma_f32_16x16x32_bf16(a0, bfr, acc[0][nt], 0, 0, 0);
            acc[1][nt] = __builtin_amdgcn_mfma_f32_16x16x32_bf16(a1, bfr, acc[1][nt], 0, 0, 0);
        }
    }

    // epilogue 1: bias + relu + bf16, store transposed [l][o]
    #pragma unroll
    for (int i = 0; i < 2; ++i) {
        const int o0 = m0 + 16 * i + 4 * q;
        #pragma unroll
        for (int nt = 0; nt < 4; ++nt) {
            const f32x4 v = acc[i][nt];
            bf16x4 hv;
            #pragma unroll
            for (int r = 0; r < 4; ++r) {
                float x = v[r] + B1s[o0 + r];
                hv[r] = (bf16)fmaxf(x, 0.f);
            }
            *(bf16x4*)(&H1T[(nt * 16 + m) * YSTR + o0]) = hv;
        }
    }
    __syncthreads();

    // ---- layer 2: y2 = relu(W2 @ h1 + b2) ----
    f32x4 acc2[2][4];
    #pragma unroll
    for (int i = 0; i < 2; ++i)
        #pragma unroll
        for (int nt = 0; nt < 4; ++nt) acc2[i][nt] = (f32x4){0.f, 0.f, 0.f, 0.f};

    #pragma unroll
    for (int kb = 0; kb < 4; ++kb) {
        const bf16x8 a0 = *(const bf16x8*)(w2b + (size_t)(m0 + m)      * H_ + kb * 32 + q * 8);
        const bf16x8 a1 = *(const bf16x8*)(w2b + (size_t)(m0 + 16 + m) * H_ + kb * 32 + q * 8);
        #pragma unroll
        for (int nt = 0; nt < 4; ++nt) {
            const bf16x8 bfr = *(const bf16x8*)(&H1T[(nt * 16 + m) * YSTR + kb * 32 + q * 8]);
            acc2[0][nt] = __builtin_amdgcn_mfma_f32_16x16x32_bf16(a0, bfr, acc2[0][nt], 0, 0, 0);
            acc2[1][nt] = __builtin_amdgcn_mfma_f32_16x16x32_bf16(a1, bfr, acc2[1][nt], 0, 0, 0);
        }
    }

    // epilogue 2: bias + relu, fp32 store to (B,H,L)
    #pragma unroll
    for (int i = 0; i < 2; ++i) {
        const int o0 = m0 + 16 * i + 4 * q;
        #pragma unroll
        for (int nt = 0; nt < 4; ++nt) {
            const f32x4 v = acc2[i][nt];
            #pragma unroll
            for (int r = 0; r < 4; ++r) {
                float x = v[r] + B2s[o0 + r];
                x = fmaxf(x, 0.f);
                out[((size_t)b * H_ + o0 + r) * L_ + l0 + nt * 16 + m] = x;
            }
        }
    }
}

// ---------------------------------------------------------------- launch ----
extern "C" void kernel_launch(void* const* d_in, const int* in_sizes, int n_in,
                              void* d_out, int out_size, void* d_ws, size_t ws_size,
                              hipStream_t stream) {
    const float* u   = (const float*)d_in[0];
    const float* lre = (const float*)d_in[1];
    const float* lim = (const float*)d_in[2];
    const float* wre = (const float*)d_in[3];
    const float* wim = (const float*)d_in[4];
    const float* dv  = (const float*)d_in[5];
    const float* w1  = (const float*)d_in[6];
    const float* b1  = (const float*)d_in[7];
    const float* w2  = (const float*)d_in[8];
    const float* b2  = (const float*)d_in[9];
    float* out = (float*)d_out;

    // ws layout: y_bf16 (B*H*L*2 = 33.55 MB) | W1 bf16 (32 KB) | W2 bf16 (32 KB)
    bf16* ybf = (bf16*)d_ws;
    bf16* w1b = (bf16*)((char*)d_ws + (size_t)B_ * H_ * L_ * sizeof(bf16));
    bf16* w2b = w1b + H_ * H_;

    hipLaunchKernelGGL(k_prep, dim3((H_ * H_ + 255) / 256), dim3(256), 0, stream,
                       w1, w2, w1b, w2b);
    hipLaunchKernelGGL(k_ssm, dim3(B_ * H_), dim3(64), 0, stream,
                       u, lre, lim, wre, wim, dv, ybf);
    hipLaunchKernelGGL(k_mlp, dim3(B_ * (L_ / 64)), dim3(256), 0, stream,
                       ybf, w1b, w2b, b1, b2, out);
}

// Round 2
// 136.735 us; speedup vs baseline: 1.6603x; 1.6603x over previous
//
#include <hip/hip_runtime.h>
#include <hip/hip_bf16.h>

#define B_ 16
#define H_ 128
#define L_ 4096
#define N_ 64
#define DT_ 0.01f

typedef __bf16 bf16;
typedef __bf16 bf16x8 __attribute__((ext_vector_type(8)));
typedef __bf16 bf16x4 __attribute__((ext_vector_type(4)));
typedef float f32x4 __attribute__((ext_vector_type(4)));

// ---------------------------------------------------------------- k_prep ----
__global__ void k_prep(const float* __restrict__ w1, const float* __restrict__ w2,
                       bf16* __restrict__ w1b, bf16* __restrict__ w2b) {
    int i = blockIdx.x * blockDim.x + threadIdx.x;
    if (i < H_ * H_) {
        w1b[i] = (bf16)w1[i];
        w2b[i] = (bf16)w2[i];
    }
}

// --------------------------------------------------------------- k_prep2 ----
// Per h: build chunked-scan tables. A = exp(DT*lambda).
//  Pbf[h][row][j] (A-op, 128x64): row n   : Re(A^{63-j}), row 64+n: Im(A^{63-j})
//  Qbf[h][dlt][k] (A-op, 64x128): k=2n: Re(W*A^{dlt+1}), k=2n+1: -Im(W*A^{dlt+1})
//  tap[h][dlt] = sum_n Re(W_n * A_n^dlt)   (Toeplitz taps)
//  acre/acim[h][n] = A^64
__global__ __launch_bounds__(64) void k_prep2(
        const float* __restrict__ lre, const float* __restrict__ lim,
        const float* __restrict__ wre, const float* __restrict__ wim,
        bf16* __restrict__ Pbf, bf16* __restrict__ Qbf,
        float* __restrict__ tap, float* __restrict__ acre, float* __restrict__ acim) {
    __shared__ float red[64 * 65];
    const int h = blockIdx.x, n = threadIdx.x;
    const float lr = lre[h * 64 + n] * DT_, li = lim[h * 64 + n] * DT_;
    const float e = expf(lr);
    const float ar = e * cosf(li), ai = e * sinf(li);
    const float wr = wre[h * 64 + n], wi = wim[h * 64 + n];
    const float war = wr * ar - wi * ai;   // W*A
    const float wai = wr * ai + wi * ar;
    float pr = 1.f, pi = 0.f;              // p = A^dlt
    bf16* Ph = Pbf + (size_t)h * 128 * 64;
    bf16* Qh = Qbf + (size_t)h * 64 * 128;
    for (int dlt = 0; dlt < 64; ++dlt) {
        Ph[(size_t)n * 64 + (63 - dlt)]        = (bf16)pr;
        Ph[(size_t)(64 + n) * 64 + (63 - dlt)] = (bf16)pi;
        Qh[(size_t)dlt * 128 + 2 * n]     = (bf16)(war * pr - wai * pi);
        Qh[(size_t)dlt * 128 + 2 * n + 1] = (bf16)(-(war * pi + wai * pr));
        red[dlt * 65 + n] = wr * pr - wi * pi;
        const float npr = ar * pr - ai * pi;
        const float npi = ar * pi + ai * pr;
        pr = npr; pi = npi;
    }
    acre[h * 64 + n] = pr;   // A^64
    acim[h * 64 + n] = pi;
    __syncthreads();
    float s = 0.f;
    #pragma unroll
    for (int k = 0; k < 64; ++k) s += red[n * 65 + k];
    tap[h * 64 + n] = s;     // tap[dlt = n]
}

// ---------------------------------------------------------------- k_ssm2 ----
// Chunked scan: block = (b,h), 4 waves. C=64 chunks of 64.
//  1. stage u -> Ubf[c][j] bf16 (XOR-swizzled B-op), build T (Toeplitz+d) in LDS
//  2. MFMA-1: Ctr[2n][c] = P @ U          (M=128,K=64,N=64)
//  3. wave0: scan over c -> Sbf[c][2n] bf16 (states ENTERING chunk c)
//  4. MFMA-2: y[dlt][c] = Q @ S + T @ U   (M=64,K=128+64,N=64)
//  5. y -> LDS transpose -> coalesced bf16 store
#define USWZ(c, k) ((c) * 64 + (((((k) >> 4) ^ ((c) & 3)) << 4) | ((k) & 15)))
#define SSWZ(c, k) ((c) * 128 + (((((k) >> 4) ^ ((c) & 7)) << 4) | ((k) & 15)))
__global__ __launch_bounds__(256) void k_ssm2(
        const float* __restrict__ u, const float* __restrict__ dv,
        const bf16* __restrict__ Pbf, const bf16* __restrict__ Qbf,
        const float* __restrict__ tap,
        const float* __restrict__ acre, const float* __restrict__ acim,
        bf16* __restrict__ ybf) {
    __shared__ bf16  Ubf[64 * 64];     //  8 KB
    __shared__ float Ctr[128 * 65];    // 32.5 KB (reused as Ybf in epilogue)
    __shared__ bf16  Sbf[64 * 128];    // 16 KB
    __shared__ bf16  Tm[64 * 72];      //  9 KB

    const int tid = threadIdx.x;
    const int bh  = blockIdx.x;
    const int h   = bh & (H_ - 1);
    const float* __restrict__ up = u + (size_t)bh * L_;

    // ---- stage u (coalesced float4) -> Ubf bf16 swizzled ----
    {
        const int c = tid >> 2, j0 = (tid & 3) << 4;
        const float4* src = (const float4*)(up + c * 64 + j0);
        bf16x8 t0, t1;
        #pragma unroll
        for (int v = 0; v < 2; ++v) {
            float4 f0 = src[2 * v], f1 = src[2 * v + 1];
            bf16x8 t;
            t[0] = (bf16)f0.x; t[1] = (bf16)f0.y; t[2] = (bf16)f0.z; t[3] = (bf16)f0.w;
            t[4] = (bf16)f1.x; t[5] = (bf16)f1.y; t[6] = (bf16)f1.z; t[7] = (bf16)f1.w;
            if (v == 0) t0 = t; else t1 = t;
        }
        bf16* dst = &Ubf[USWZ(c, j0)];
        ((bf16x8*)dst)[0] = t0;
        ((bf16x8*)dst)[1] = t1;
    }
    // ---- build Toeplitz T[dlt][j] = tap[dlt-j] (+d on diag), bf16, pad 72 ----
    {
        const int dlt = tid >> 2, j0 = (tid & 3) << 4;
        const float* tp = tap + h * 64;
        const float dh = dv[h];
        bf16x8 t0, t1;
        #pragma unroll
        for (int e = 0; e < 16; ++e) {
            const int j = j0 + e;
            float v = (j <= dlt) ? tp[dlt - j] : 0.f;
            if (j == dlt) v += dh;
            if (e < 8) t0[e] = (bf16)v; else t1[e - 8] = (bf16)v;
        }
        bf16* dst = &Tm[dlt * 72 + j0];
        ((bf16x8*)dst)[0] = t0;
        ((bf16x8*)dst)[1] = t1;
    }
    __syncthreads();

    const int lane = tid & 63, wv = tid >> 6;
    const int cl = lane & 15, q = lane >> 4;

    // ---- MFMA-1: contributions Ctr[row][c], rows 0-63 Re, 64-127 Im ----
    {
        f32x4 acc[2][4];
        #pragma unroll
        for (int i = 0; i < 2; ++i)
            #pragma unroll
            for (int nt = 0; nt < 4; ++nt) acc[i][nt] = (f32x4){0.f, 0.f, 0.f, 0.f};
        const bf16* Ph = Pbf + (size_t)h * 128 * 64;
        #pragma unroll
        for (int ks = 0; ks < 2; ++ks) {
            const int k0 = ks * 32 + q * 8;
            const bf16x8 a0 = *(const bf16x8*)(Ph + (size_t)(wv * 32 + cl) * 64 + k0);
            const bf16x8 a1 = *(const bf16x8*)(Ph + (size_t)(wv * 32 + 16 + cl) * 64 + k0);
            #pragma unroll
            for (int nt = 0; nt < 4; ++nt) {
                const int c = nt * 16 + cl;
                const bf16x8 bfr = *(const bf16x8*)(&Ubf[USWZ(c, k0)]);
                acc[0][nt] = __builtin_amdgcn_mfma_f32_16x16x32_bf16(a0, bfr, acc[0][nt], 0, 0, 0);
                acc[1][nt] = __builtin_amdgcn_mfma_f32_16x16x32_bf16(a1, bfr, acc[1][nt], 0, 0, 0);
            }
        }
        #pragma unroll
        for (int mt = 0; mt < 2; ++mt)
            #pragma unroll
            for (int nt = 0; nt < 4; ++nt)
                #pragma unroll
                for (int r = 0; r < 4; ++r)
                    Ctr[(wv * 32 + mt * 16 + q * 4 + r) * 65 + nt * 16 + cl] = acc[mt][nt][r];
    }
    __syncthreads();

    // ---- scan (wave 0): S[c] = state entering chunk c; s' = A^64 s + contrib ----
    if (wv == 0) {
        const int n = lane;
        const float ar = acre[h * 64 + n], ai = acim[h * 64 + n];
        float sr = 0.f, si = 0.f;
        #pragma unroll 8
        for (int c = 0; c < 64; ++c) {
            bf16* sp = &Sbf[SSWZ(c, 2 * n)];
            sp[0] = (bf16)sr;
            sp[1] = (bf16)si;
            const float cr = Ctr[n * 65 + c];
            const float ci = Ctr[(64 + n) * 65 + c];
            const float nr = fmaf(ar, sr, fmaf(-ai, si, cr));
            const float ni = fmaf(ar, si, fmaf(ai, sr, ci));
            sr = nr; si = ni;
        }
    }
    __syncthreads();

    // ---- MFMA-2: y[dlt][c] = Q@S + T@U; wave wv owns dlt rows [16wv,16wv+16) ----
    {
        f32x4 acc[4];
        #pragma unroll
        for (int nt = 0; nt < 4; ++nt) acc[nt] = (f32x4){0.f, 0.f, 0.f, 0.f};
        const bf16* Qh = Qbf + (size_t)h * 64 * 128;
        #pragma unroll
        for (int ks = 0; ks < 4; ++ks) {
            const int k0 = ks * 32 + q * 8;
            const bf16x8 a = *(const bf16x8*)(Qh + (size_t)(wv * 16 + cl) * 128 + k0);
            #pragma unroll
            for (int nt = 0; nt < 4; ++nt) {
                const int c = nt * 16 + cl;
                const bf16x8 bfr = *(const bf16x8*)(&Sbf[SSWZ(c, k0)]);
                acc[nt] = __builtin_amdgcn_mfma_f32_16x16x32_bf16(a, bfr, acc[nt], 0, 0, 0);
            }
        }
        #pragma unroll
        for (int ks = 0; ks < 2; ++ks) {
            const int k0 = ks * 32 + q * 8;
            const bf16x8 a = *(const bf16x8*)(&Tm[(wv * 16 + cl) * 72 + k0]);
            #pragma unroll
            for (int nt = 0; nt < 4; ++nt) {
                const int c = nt * 16 + cl;
                const bf16x8 bfr = *(const bf16x8*)(&Ubf[USWZ(c, k0)]);
                acc[nt] = __builtin_amdgcn_mfma_f32_16x16x32_bf16(a, bfr, acc[nt], 0, 0, 0);
            }
        }
        // epilogue: Ybf[c][dlt] (stride 68), aliasing Ctr (dead after scan)
        bf16* Yb = (bf16*)Ctr;
        #pragma unroll
        for (int nt = 0; nt < 4; ++nt) {
            const int c = nt * 16 + cl;
            bf16x4 yv;
            #pragma unroll
            for (int r = 0; r < 4; ++r) yv[r] = (bf16)acc[nt][r];
            *(bf16x4*)(&Yb[c * 68 + wv * 16 + q * 4]) = yv;
        }
    }
    __syncthreads();

    // ---- coalesced store ----
    {
        const bf16* Yb = (const bf16*)Ctr;
        const int c = tid >> 2, s0 = (tid & 3) << 4;
        bf16x4 v0 = *(const bf16x4*)(&Yb[c * 68 + s0 + 0]);
        bf16x4 v1 = *(const bf16x4*)(&Yb[c * 68 + s0 + 4]);
        bf16x4 v2 = *(const bf16x4*)(&Yb[c * 68 + s0 + 8]);
        bf16x4 v3 = *(const bf16x4*)(&Yb[c * 68 + s0 + 12]);
        bf16* yp = ybf + (size_t)bh * L_ + c * 64 + s0;
        ((bf16x4*)yp)[0] = v0; ((bf16x4*)yp)[1] = v1;
        ((bf16x4*)yp)[2] = v2; ((bf16x4*)yp)[3] = v3;
    }
}

// ----------------------------------------------------------------- k_mlp ----
#define YSTR 136
__global__ __launch_bounds__(256) void k_mlp(
        const bf16* __restrict__ ybf,
        const bf16* __restrict__ w1b, const bf16* __restrict__ w2b,
        const float* __restrict__ b1, const float* __restrict__ b2,
        float* __restrict__ out) {
    __shared__ bf16 YT [64 * YSTR];
    __shared__ bf16 H1T[64 * YSTR];
    __shared__ float B1s[H_], B2s[H_];

    const int tid = threadIdx.x;
    const int b   = blockIdx.x >> 6;
    const int lt  = blockIdx.x & 63;
    const int l0  = lt * 64;

    if (tid < H_) { B1s[tid] = b1[tid]; B2s[tid] = b2[tid]; }

    {
        const int h  = tid >> 1;
        const int lh = (tid & 1) * 32;
        const bf16x8* src = (const bf16x8*)(ybf + ((size_t)b * H_ + h) * L_ + l0 + lh);
        #pragma unroll
        for (int v = 0; v < 4; ++v) {
            bf16x8 d = src[v];
            #pragma unroll
            for (int e = 0; e < 8; ++e) YT[(lh + v * 8 + e) * YSTR + h] = d[e];
        }
    }
    __syncthreads();

    const int lane = tid & 63;
    const int wv   = tid >> 6;
    const int m    = lane & 15;
    const int q    = lane >> 4;
    const int m0   = wv * 32;

    f32x4 acc[2][4];
    #pragma unroll
    for (int i = 0; i < 2; ++i)
        #pragma unroll
        for (int nt = 0; nt < 4; ++nt) acc[i][nt] = (f32x4){0.f, 0.f, 0.f, 0.f};

    #pragma unroll
    for (int kb = 0; kb < 4; ++kb) {
        const bf16x8 a0 = *(const bf16x8*)(w1b + (size_t)(m0 + m)      * H_ + kb * 32 + q * 8);
        const bf16x8 a1 = *(const bf16x8*)(w1b + (size_t)(m0 + 16 + m) * H_ + kb * 32 + q * 8);
        #pragma unroll
        for (int nt = 0; nt < 4; ++nt) {
            const bf16x8 bfr = *(const bf16x8*)(&YT[(nt * 16 + m) * YSTR + kb * 32 + q * 8]);
            acc[0][nt] = __builtin_amdgcn_mfma_f32_16x16x32_bf16(a0, bfr, acc[0][nt], 0, 0, 0);
            acc[1][nt] = __builtin_amdgcn_mfma_f32_16x16x32_bf16(a1, bfr, acc[1][nt], 0, 0, 0);
        }
    }

    #pragma unroll
    for (int i = 0; i < 2; ++i) {
        const int o0 = m0 + 16 * i + 4 * q;
        #pragma unroll
        for (int nt = 0; nt < 4; ++nt) {
            const f32x4 v = acc[i][nt];
            bf16x4 hv;
            #pragma unroll
            for (int r = 0; r < 4; ++r) {
                float x = v[r] + B1s[o0 + r];
                hv[r] = (bf16)fmaxf(x, 0.f);
            }
            *(bf16x4*)(&H1T[(nt * 16 + m) * YSTR + o0]) = hv;
        }
    }
    __syncthreads();

    f32x4 acc2[2][4];
    #pragma unroll
    for (int i = 0; i < 2; ++i)
        #pragma unroll
        for (int nt = 0; nt < 4; ++nt) acc2[i][nt] = (f32x4){0.f, 0.f, 0.f, 0.f};

    #pragma unroll
    for (int kb = 0; kb < 4; ++kb) {
        const bf16x8 a0 = *(const bf16x8*)(w2b + (size_t)(m0 + m)      * H_ + kb * 32 + q * 8);
        const bf16x8 a1 = *(const bf16x8*)(w2b + (size_t)(m0 + 16 + m) * H_ + kb * 32 + q * 8);
        #pragma unroll
        for (int nt = 0; nt < 4; ++nt) {
            const bf16x8 bfr = *(const bf16x8*)(&H1T[(nt * 16 + m) * YSTR + kb * 32 + q * 8]);
            acc2[0][nt] = __builtin_amdgcn_mfma_f32_16x16x32_bf16(a0, bfr, acc2[0][nt], 0, 0, 0);
            acc2[1][nt] = __builtin_amdgcn_mfma_f32_16x16x32_bf16(a1, bfr, acc2[1][nt], 0, 0, 0);
        }
    }

    #pragma unroll
    for (int i = 0; i < 2; ++i) {
        const int o0 = m0 + 16 * i + 4 * q;
        #pragma unroll
        for (int nt = 0; nt < 4; ++nt) {
            const f32x4 v = acc2[i][nt];
            #pragma unroll
            for (int r = 0; r < 4; ++r) {
                float x = v[r] + B2s[o0 + r];
                x = fmaxf(x, 0.f);
                out[((size_t)b * H_ + o0 + r) * L_ + l0 + nt * 16 + m] = x;
            }
        }
    }
}

// ---------------------------------------------------------------- launch ----
extern "C" void kernel_launch(void* const* d_in, const int* in_sizes, int n_in,
                              void* d_out, int out_size, void* d_ws, size_t ws_size,
                              hipStream_t stream) {
    const float* u   = (const float*)d_in[0];
    const float* lre = (const float*)d_in[1];
    const float* lim = (const float*)d_in[2];
    const float* wre = (const float*)d_in[3];
    const float* wim = (const float*)d_in[4];
    const float* dv  = (const float*)d_in[5];
    const float* w1  = (const float*)d_in[6];
    const float* b1  = (const float*)d_in[7];
    const float* w2  = (const float*)d_in[8];
    const float* b2  = (const float*)d_in[9];
    float* out = (float*)d_out;

    char* ws = (char*)d_ws;
    bf16*  ybf  = (bf16*)ws;                 ws += (size_t)B_ * H_ * L_ * 2;  // 33.55 MB
    bf16*  w1b  = (bf16*)ws;                 ws += H_ * H_ * 2;
    bf16*  w2b  = (bf16*)ws;                 ws += H_ * H_ * 2;
    bf16*  Pbf  = (bf16*)ws;                 ws += (size_t)H_ * 128 * 64 * 2; // 2 MB
    bf16*  Qbf  = (bf16*)ws;                 ws += (size_t)H_ * 64 * 128 * 2; // 2 MB
    float* tap  = (float*)ws;                ws += H_ * 64 * 4;
    float* acre = (float*)ws;                ws += H_ * 64 * 4;
    float* acim = (float*)ws;                ws += H_ * 64 * 4;

    hipLaunchKernelGGL(k_prep, dim3((H_ * H_ + 255) / 256), dim3(256), 0, stream,
                       w1, w2, w1b, w2b);
    hipLaunchKernelGGL(k_prep2, dim3(H_), dim3(64), 0, stream,
                       lre, lim, wre, wim, Pbf, Qbf, tap, acre, acim);
    hipLaunchKernelGGL(k_ssm2, dim3(B_ * H_), dim3(256), 0, stream,
                       u, dv, Pbf, Qbf, tap, acre, acim, ybf);
    hipLaunchKernelGGL(k_mlp, dim3(B_ * (L_ / 64)), dim3(256), 0, stream,
                       ybf, w1b, w2b, b1, b2, out);
}

// Round 3
// 136.042 us; speedup vs baseline: 1.6687x; 1.0051x over previous
//
#include <hip/hip_runtime.h>
#include <hip/hip_bf16.h>

#define B_ 16
#define H_ 128
#define L_ 4096
#define N_ 64
#define DT_ 0.01f

typedef __bf16 bf16;
typedef __bf16 bf16x8 __attribute__((ext_vector_type(8)));
typedef __bf16 bf16x4 __attribute__((ext_vector_type(4)));
typedef float f32x4 __attribute__((ext_vector_type(4)));

// ---------------------------------------------------------------- k_prep ----
// One block per h (128 blocks, 64 threads). Builds all tables + casts weights.
//  Pbf[h][row][j] (A-op, 128x64): row n: Re(A^{63-j}), row 64+n: Im(A^{63-j})
//  Qbf[h][dlt][k] (A-op, 64x128): k=2n: Re(W*A^{dlt+1}), k=2n+1: -Im(...)
//  tap[h][dlt] = sum_n Re(W_n A_n^dlt);  acre/acim = A^64
// P/Q staged via LDS for coalesced dwordx4 global stores.
__global__ __launch_bounds__(64) void k_prep(
        const float* __restrict__ lre, const float* __restrict__ lim,
        const float* __restrict__ wre, const float* __restrict__ wim,
        const float* __restrict__ w1, const float* __restrict__ w2,
        bf16* __restrict__ w1b, bf16* __restrict__ w2b,
        bf16* __restrict__ Pbf, bf16* __restrict__ Qbf,
        float* __restrict__ tap, float* __restrict__ acre, float* __restrict__ acim) {
    __shared__ bf16  Pl[128 * 72];    // stride 72: 16B-aligned rows
    __shared__ bf16  Ql[64 * 136];    // stride 136: 16B-aligned rows
    __shared__ float red[64 * 65];

    const int h = blockIdx.x, n = threadIdx.x;

    // weight cast (row h of each)
    w1b[h * H_ + n]      = (bf16)w1[h * H_ + n];
    w1b[h * H_ + 64 + n] = (bf16)w1[h * H_ + 64 + n];
    w2b[h * H_ + n]      = (bf16)w2[h * H_ + n];
    w2b[h * H_ + 64 + n] = (bf16)w2[h * H_ + 64 + n];

    const float lr = lre[h * 64 + n] * DT_, li = lim[h * 64 + n] * DT_;
    const float e = expf(lr);
    const float ar = e * cosf(li), ai = e * sinf(li);
    const float wr = wre[h * 64 + n], wi = wim[h * 64 + n];
    const float war = wr * ar - wi * ai;   // W*A
    const float wai = wr * ai + wi * ar;
    float pr = 1.f, pi = 0.f;              // p = A^dlt
    for (int dlt = 0; dlt < 64; ++dlt) {
        Pl[n * 72 + (63 - dlt)]        = (bf16)pr;
        Pl[(64 + n) * 72 + (63 - dlt)] = (bf16)pi;
        bf16 q0 = (bf16)(war * pr - wai * pi);
        bf16 q1 = (bf16)(-(war * pi + wai * pr));
        Ql[dlt * 136 + 2 * n]     = q0;
        Ql[dlt * 136 + 2 * n + 1] = q1;
        red[dlt * 65 + n] = wr * pr - wi * pi;
        const float npr = ar * pr - ai * pi;
        const float npi = ar * pi + ai * pr;
        pr = npr; pi = npi;
    }
    acre[h * 64 + n] = pr;   // A^64
    acim[h * 64 + n] = pi;
    __syncthreads();

    float s = 0.f;
    #pragma unroll
    for (int k = 0; k < 64; ++k) s += red[n * 65 + k];
    tap[h * 64 + n] = s;

    // coalesced table writes: 8192 bf16 each, 16 x (64 lanes x 16B)
    bf16* Ph = Pbf + (size_t)h * 128 * 64;
    bf16* Qh = Qbf + (size_t)h * 64 * 128;
    #pragma unroll
    for (int i = 0; i < 16; ++i) {
        const int flat = i * 512 + n * 8;
        {
            const int row = flat >> 6, col = flat & 63;
            bf16x8 v = *(const bf16x8*)(&Pl[row * 72 + col]);
            *(bf16x8*)(Ph + flat) = v;
        }
        {
            const int row = flat >> 7, col = flat & 127;
            bf16x8 v = *(const bf16x8*)(&Ql[row * 136 + col]);
            *(bf16x8*)(Qh + flat) = v;
        }
    }
}

// ---------------------------------------------------------------- k_ssm2 ----
// Chunked scan, block = (b,h), 8 waves (512 threads). C=64 chunks of 64.
#define USWZ(c, k) ((c) * 64 + (((((k) >> 4) ^ ((c) & 3)) << 4) | ((k) & 15)))
#define SSWZ(c, k) ((c) * 128 + (((((k) >> 4) ^ ((c) & 7)) << 4) | ((k) & 15)))
__global__ __launch_bounds__(512, 4) void k_ssm2(
        const float* __restrict__ u, const float* __restrict__ dv,
        const bf16* __restrict__ Pbf, const bf16* __restrict__ Qbf,
        const float* __restrict__ tap,
        const float* __restrict__ acre, const float* __restrict__ acim,
        bf16* __restrict__ ybf) {
    __shared__ bf16  Ubf[64 * 64];     //  8 KB
    __shared__ float Ctr[128 * 65];    // 33.3 KB (aliased as Yb stride-72 in epilogue)
    __shared__ bf16  Sbf[64 * 128];    // 16 KB
    __shared__ bf16  Tm[64 * 72];      //  9 KB

    const int tid = threadIdx.x;
    const int bh  = blockIdx.x;
    const int h   = bh & (H_ - 1);
    const float* __restrict__ up = u + (size_t)bh * L_;

    // ---- stage u (fully coalesced) -> Ubf bf16 swizzled ----
    {
        const int c = tid >> 3, j0 = (tid & 7) << 3;
        const float4* src = (const float4*)(up + c * 64 + j0);
        float4 f0 = src[0], f1 = src[1];
        bf16x8 t;
        t[0] = (bf16)f0.x; t[1] = (bf16)f0.y; t[2] = (bf16)f0.z; t[3] = (bf16)f0.w;
        t[4] = (bf16)f1.x; t[5] = (bf16)f1.y; t[6] = (bf16)f1.z; t[7] = (bf16)f1.w;
        *(bf16x8*)(&Ubf[USWZ(c, j0)]) = t;
    }
    // ---- Toeplitz T[dlt][j] = tap[dlt-j] (+d on diag) ----
    {
        const int dlt = tid >> 3, j0 = (tid & 7) << 3;
        const float* tp = tap + h * 64;
        const float dh = dv[h];
        bf16x8 t;
        #pragma unroll
        for (int e = 0; e < 8; ++e) {
            const int j = j0 + e;
            float v = (j <= dlt) ? tp[dlt - j] : 0.f;
            if (j == dlt) v += dh;
            t[e] = (bf16)v;
        }
        *(bf16x8*)(&Tm[dlt * 72 + j0]) = t;
    }
    __syncthreads();

    const int lane = tid & 63, wv = tid >> 6;        // wv in [0,8)
    const int cl = lane & 15, q = lane >> 4;

    // ---- MFMA-1: Ctr[row][c] = P @ U; wave wv owns rows [16wv,16wv+16) ----
    {
        f32x4 acc[4];
        #pragma unroll
        for (int nt = 0; nt < 4; ++nt) acc[nt] = (f32x4){0.f, 0.f, 0.f, 0.f};
        const bf16* Ph = Pbf + (size_t)h * 128 * 64;
        #pragma unroll
        for (int ks = 0; ks < 2; ++ks) {
            const int k0 = ks * 32 + q * 8;
            const bf16x8 a = *(const bf16x8*)(Ph + (size_t)(wv * 16 + cl) * 64 + k0);
            #pragma unroll
            for (int nt = 0; nt < 4; ++nt) {
                const int c = nt * 16 + cl;
                const bf16x8 bfr = *(const bf16x8*)(&Ubf[USWZ(c, k0)]);
                acc[nt] = __builtin_amdgcn_mfma_f32_16x16x32_bf16(a, bfr, acc[nt], 0, 0, 0);
            }
        }
        #pragma unroll
        for (int nt = 0; nt < 4; ++nt)
            #pragma unroll
            for (int r = 0; r < 4; ++r)
                Ctr[(wv * 16 + q * 4 + r) * 65 + nt * 16 + cl] = acc[nt][r];
    }
    __syncthreads();

    // ---- scan (wave 0): states entering each chunk ----
    if (wv == 0) {
        const int n = lane;
        const float ar = acre[h * 64 + n], ai = acim[h * 64 + n];
        float sr = 0.f, si = 0.f;
        #pragma unroll 8
        for (int c = 0; c < 64; ++c) {
            bf16* sp = &Sbf[SSWZ(c, 2 * n)];
            sp[0] = (bf16)sr;
            sp[1] = (bf16)si;
            const float cr = Ctr[n * 65 + c];
            const float ci = Ctr[(64 + n) * 65 + c];
            const float nr = fmaf(ar, sr, fmaf(-ai, si, cr));
            const float ni = fmaf(ar, si, fmaf(ai, sr, ci));
            sr = nr; si = ni;
        }
    }
    __syncthreads();

    // ---- MFMA-2: y[dlt][c] = Q@S + T@U; wave wv -> m-tile wv>>1, n-tiles (wv&1)*2+{0,1}
    {
        const int mt  = wv >> 1;
        const int nt0 = (wv & 1) * 2;
        f32x4 acc[2];
        acc[0] = (f32x4){0.f, 0.f, 0.f, 0.f};
        acc[1] = (f32x4){0.f, 0.f, 0.f, 0.f};
        const bf16* Qh = Qbf + (size_t)h * 64 * 128;
        #pragma unroll
        for (int ks = 0; ks < 4; ++ks) {
            const int k0 = ks * 32 + q * 8;
            const bf16x8 a = *(const bf16x8*)(Qh + (size_t)(mt * 16 + cl) * 128 + k0);
            #pragma unroll
            for (int j = 0; j < 2; ++j) {
                const int c = (nt0 + j) * 16 + cl;
                const bf16x8 bfr = *(const bf16x8*)(&Sbf[SSWZ(c, k0)]);
                acc[j] = __builtin_amdgcn_mfma_f32_16x16x32_bf16(a, bfr, acc[j], 0, 0, 0);
            }
        }
        #pragma unroll
        for (int ks = 0; ks < 2; ++ks) {
            const int k0 = ks * 32 + q * 8;
            const bf16x8 a = *(const bf16x8*)(&Tm[(mt * 16 + cl) * 72 + k0]);
            #pragma unroll
            for (int j = 0; j < 2; ++j) {
                const int c = (nt0 + j) * 16 + cl;
                const bf16x8 bfr = *(const bf16x8*)(&Ubf[USWZ(c, k0)]);
                acc[j] = __builtin_amdgcn_mfma_f32_16x16x32_bf16(a, bfr, acc[j], 0, 0, 0);
            }
        }
        // Yb[c][dlt] stride 72 (16B-aligned), aliasing Ctr (dead after scan)
        bf16* Yb = (bf16*)Ctr;
        #pragma unroll
        for (int j = 0; j < 2; ++j) {
            const int c = (nt0 + j) * 16 + cl;
            bf16x4 yv;
            #pragma unroll
            for (int r = 0; r < 4; ++r) yv[r] = (bf16)acc[j][r];
            *(bf16x4*)(&Yb[c * 72 + mt * 16 + q * 4]) = yv;
        }
    }
    __syncthreads();

    // ---- coalesced store: one bf16x8 per thread ----
    {
        const bf16* Yb = (const bf16*)Ctr;
        const int c = tid >> 3, s0 = (tid & 7) << 3;
        bf16x8 v = *(const bf16x8*)(&Yb[c * 72 + s0]);
        *(bf16x8*)(ybf + (size_t)bh * L_ + c * 64 + s0) = v;
    }
}

// ----------------------------------------------------------------- k_mlp ----
// Fused 2-layer MLP; H1T aliases YT (extra barrier) -> 19.4 KB LDS.
#define YSTR 136
__global__ __launch_bounds__(256, 6) void k_mlp(
        const bf16* __restrict__ ybf,
        const bf16* __restrict__ w1b, const bf16* __restrict__ w2b,
        const float* __restrict__ b1, const float* __restrict__ b2,
        float* __restrict__ out) {
    __shared__ bf16 YT[64 * YSTR];    // y tile transposed [l][h]; reused as H1T
    __shared__ float B1s[H_], B2s[H_];

    const int tid = threadIdx.x;
    const int b   = blockIdx.x >> 6;
    const int lt  = blockIdx.x & 63;
    const int l0  = lt * 64;

    if (tid < H_) { B1s[tid] = b1[tid]; B2s[tid] = b2[tid]; }

    {
        const int h  = tid >> 1;
        const int lh = (tid & 1) * 32;
        const bf16x8* src = (const bf16x8*)(ybf + ((size_t)b * H_ + h) * L_ + l0 + lh);
        #pragma unroll
        for (int v = 0; v < 4; ++v) {
            bf16x8 d = src[v];
            #pragma unroll
            for (int e = 0; e < 8; ++e) YT[(lh + v * 8 + e) * YSTR + h] = d[e];
        }
    }
    __syncthreads();

    const int lane = tid & 63;
    const int wv   = tid >> 6;
    const int m    = lane & 15;
    const int q    = lane >> 4;
    const int m0   = wv * 32;

    // ---- layer 1 ----
    f32x4 acc[2][4];
    #pragma unroll
    for (int i = 0; i < 2; ++i)
        #pragma unroll
        for (int nt = 0; nt < 4; ++nt) acc[i][nt] = (f32x4){0.f, 0.f, 0.f, 0.f};

    #pragma unroll
    for (int kb = 0; kb < 4; ++kb) {
        const bf16x8 a0 = *(const bf16x8*)(w1b + (size_t)(m0 + m)      * H_ + kb * 32 + q * 8);
        const bf16x8 a1 = *(const bf16x8*)(w1b + (size_t)(m0 + 16 + m) * H_ + kb * 32 + q * 8);
        #pragma unroll
        for (int nt = 0; nt < 4; ++nt) {
            const bf16x8 bfr = *(const bf16x8*)(&YT[(nt * 16 + m) * YSTR + kb * 32 + q * 8]);
            acc[0][nt] = __builtin_amdgcn_mfma_f32_16x16x32_bf16(a0, bfr, acc[0][nt], 0, 0, 0);
            acc[1][nt] = __builtin_amdgcn_mfma_f32_16x16x32_bf16(a1, bfr, acc[1][nt], 0, 0, 0);
        }
    }
    __syncthreads();   // all YT reads done before H1T(=YT) writes

    #pragma unroll
    for (int i = 0; i < 2; ++i) {
        const int o0 = m0 + 16 * i + 4 * q;
        #pragma unroll
        for (int nt = 0; nt < 4; ++nt) {
            const f32x4 v = acc[i][nt];
            bf16x4 hv;
            #pragma unroll
            for (int r = 0; r < 4; ++r) {
                float x = v[r] + B1s[o0 + r];
                hv[r] = (bf16)fmaxf(x, 0.f);
            }
            *(bf16x4*)(&YT[(nt * 16 + m) * YSTR + o0]) = hv;
        }
    }
    __syncthreads();

    // ---- layer 2 ----
    f32x4 acc2[2][4];
    #pragma unroll
    for (int i = 0; i < 2; ++i)
        #pragma unroll
        for (int nt = 0; nt < 4; ++nt) acc2[i][nt] = (f32x4){0.f, 0.f, 0.f, 0.f};

    #pragma unroll
    for (int kb = 0; kb < 4; ++kb) {
        const bf16x8 a0 = *(const bf16x8*)(w2b + (size_t)(m0 + m)      * H_ + kb * 32 + q * 8);
        const bf16x8 a1 = *(const bf16x8*)(w2b + (size_t)(m0 + 16 + m) * H_ + kb * 32 + q * 8);
        #pragma unroll
        for (int nt = 0; nt < 4; ++nt) {
            const bf16x8 bfr = *(const bf16x8*)(&YT[(nt * 16 + m) * YSTR + kb * 32 + q * 8]);
            acc2[0][nt] = __builtin_amdgcn_mfma_f32_16x16x32_bf16(a0, bfr, acc2[0][nt], 0, 0, 0);
            acc2[1][nt] = __builtin_amdgcn_mfma_f32_16x16x32_bf16(a1, bfr, acc2[1][nt], 0, 0, 0);
        }
    }

    #pragma unroll
    for (int i = 0; i < 2; ++i) {
        const int o0 = m0 + 16 * i + 4 * q;
        #pragma unroll
        for (int nt = 0; nt < 4; ++nt) {
            const f32x4 v = acc2[i][nt];
            #pragma unroll
            for (int r = 0; r < 4; ++r) {
                float x = v[r] + B2s[o0 + r];
                x = fmaxf(x, 0.f);
                out[((size_t)b * H_ + o0 + r) * L_ + l0 + nt * 16 + m] = x;
            }
        }
    }
}

// ---------------------------------------------------------------- launch ----
extern "C" void kernel_launch(void* const* d_in, const int* in_sizes, int n_in,
                              void* d_out, int out_size, void* d_ws, size_t ws_size,
                              hipStream_t stream) {
    const float* u   = (const float*)d_in[0];
    const float* lre = (const float*)d_in[1];
    const float* lim = (const float*)d_in[2];
    const float* wre = (const float*)d_in[3];
    const float* wim = (const float*)d_in[4];
    const float* dv  = (const float*)d_in[5];
    const float* w1  = (const float*)d_in[6];
    const float* b1  = (const float*)d_in[7];
    const float* w2  = (const float*)d_in[8];
    const float* b2  = (const float*)d_in[9];
    float* out = (float*)d_out;

    char* ws = (char*)d_ws;
    bf16*  ybf  = (bf16*)ws;                 ws += (size_t)B_ * H_ * L_ * 2;  // 33.55 MB
    bf16*  w1b  = (bf16*)ws;                 ws += H_ * H_ * 2;
    bf16*  w2b  = (bf16*)ws;                 ws += H_ * H_ * 2;
    bf16*  Pbf  = (bf16*)ws;                 ws += (size_t)H_ * 128 * 64 * 2; // 2 MB
    bf16*  Qbf  = (bf16*)ws;                 ws += (size_t)H_ * 64 * 128 * 2; // 2 MB
    float* tap  = (float*)ws;                ws += H_ * 64 * 4;
    float* acre = (float*)ws;                ws += H_ * 64 * 4;
    float* acim = (float*)ws;                ws += H_ * 64 * 4;

    hipLaunchKernelGGL(k_prep, dim3(H_), dim3(64), 0, stream,
                       lre, lim, wre, wim, w1, w2, w1b, w2b,
                       Pbf, Qbf, tap, acre, acim);
    hipLaunchKernelGGL(k_ssm2, dim3(B_ * H_), dim3(512), 0, stream,
                       u, dv, Pbf, Qbf, tap, acre, acim, ybf);
    hipLaunchKernelGGL(k_mlp, dim3(B_ * (L_ / 64)), dim3(256), 0, stream,
                       ybf, w1b, w2b, b1, b2, out);
}